// Round 5
// baseline (275.396 us; speedup 1.0000x reference)
//
#include <hip/hip_runtime.h>

#define N_PTS 1000000
#define H_DIM 200
#define W_DIM 70400
#define FILL_V -9999999.0f

typedef float v2f __attribute__((ext_vector_type(2)));

__device__ __forceinline__ v2f fma2(v2f a, v2f b, v2f c) {
    return __builtin_elementwise_fma(a, b, c);   // -> v_pk_fma_f32 on gfx950
}

// ---------------------------------------------------------------------------
// Kernel A v3: TWO points per thread (R5).
// R4 post-mortem: atomic hoist + nt store = no change in mlp (87us) -> the
// stall is NOT the atomic tail. Model: weights are 2143 floats = 8.6 KB of
// s_load traffic per point against a 112-SGPR budget -- the unrolled body is
// a continuous s_load + lgkmcnt-wait stream, ~60% stall at ~3 waves/SIMD.
// Fix: amortize every weight s_load over TWO points (i=2t, 2t+1). Live state
// doubles (h1 9->18 v2f, h2 18->36 v2f) from a 60-VGPR baseline -> ~130-150
// VGPR, no spill expected (old 2-pt spill was under a fatter structure).
// All state statically indexed / named (no runtime-indexed arrays).
// Loads: input rows as v2f (contiguous 512B/wave), tindex as int4.
// nt store REVERTED (R4: +11us total -- colmax list reads pushed to HBM).
// List entry: .x = value bits, .y = (point_index << 8) | row  (row<200<256).
// Last-write-wins scatter: point survives iff no LATER point hit (row,col).
// ---------------------------------------------------------------------------
__global__ void __launch_bounds__(256) mlp_scatter_kernel(
    const float* __restrict__ input,        // [4][N]
    const int* __restrict__ tindex,         // [N][2] int32 (row, col)
    const float* __restrict__ w1, const float* __restrict__ b1,
    const float* __restrict__ w2, const float* __restrict__ b2,
    const float* __restrict__ w3, const float* __restrict__ b3,
    const float* __restrict__ w4, const float* __restrict__ b4,
    int* __restrict__ counts,               // [W]
    uint2* __restrict__ list,               // [W][maxk]
    int maxk)
{
    // empty-branch (reference: tensor_index[0,0] == -1 -> no scatter)
    if (tindex[0] == -1) return;

    const int t = blockIdx.x * 256 + threadIdx.x;
    const int i = t * 2;                    // point pair (i, i+1); N is even
    if (i >= N_PTS) return;

    // scatter-slot atomics issued first; latency hides under the MLP
    const int4 hw2 = ((const int4*)tindex)[t];   // (rowA, colA, rowB, colB)
    const int posA = atomicAdd(&counts[hw2.y], 1);
    const int posB = atomicAdd(&counts[hw2.w], 1);

    const v2f* __restrict__ w1v = (const v2f*)w1;   // rows of 4 = 2 v2f
    const v2f* __restrict__ w2v = (const v2f*)w2;   // rows of 18 = 9 v2f
    const v2f* __restrict__ w3v = (const v2f*)w3;   // rows of 36 = 18 v2f

    // input rows: 2 consecutive floats per row -> contiguous wave access
    const v2f xc0 = *(const v2f*)&input[0 * N_PTS + i];
    const v2f xc1 = *(const v2f*)&input[1 * N_PTS + i];
    const v2f xc2 = *(const v2f*)&input[2 * N_PTS + i];
    const v2f xc3 = *(const v2f*)&input[3 * N_PTS + i];
    const v2f xA01 = { xc0.x, xc1.x }, xA23 = { xc2.x, xc3.x };
    const v2f xB01 = { xc0.y, xc1.y }, xB23 = { xc2.y, xc3.y };

    // layer 1: 18 outputs, k packed; each weight fetch feeds BOTH points
    v2f h1a[9], h1b[9];
#pragma unroll
    for (int o = 0; o < 18; ++o) {
        const v2f wr0 = w1v[o * 2 + 0], wr1 = w1v[o * 2 + 1];
        v2f aA = { b1[o], 0.0f };
        v2f aB = aA;
        aA = fma2(wr0, xA01, aA); aA = fma2(wr1, xA23, aA);
        aB = fma2(wr0, xB01, aB); aB = fma2(wr1, xB23, aB);
        const float hA = fmaxf(aA.x + aA.y, 0.0f);
        const float hB = fmaxf(aB.x + aB.y, 0.0f);
        if (o & 1) { h1a[o >> 1].y = hA; h1b[o >> 1].y = hB; }
        else       { h1a[o >> 1].x = hA; h1b[o >> 1].x = hB; }
    }

    // layer 2: 36 outputs, k packed (18 -> 9 pairs)
    v2f h2a[18], h2b[18];
#pragma unroll
    for (int o = 0; o < 36; ++o) {
        v2f aA = { b2[o], 0.0f };
        v2f aB = aA;
#pragma unroll
        for (int q = 0; q < 9; ++q) {
            const v2f wq = w2v[o * 9 + q];
            aA = fma2(wq, h1a[q], aA);
            aB = fma2(wq, h1b[q], aB);
        }
        const float hA = fmaxf(aA.x + aA.y, 0.0f);
        const float hB = fmaxf(aB.x + aB.y, 0.0f);
        if (o & 1) { h2a[o >> 1].y = hA; h2b[o >> 1].y = hB; }
        else       { h2a[o >> 1].x = hA; h2b[o >> 1].x = hB; }
    }

    // layer 3 (k packed, 36 -> 18 pairs) with layer 4 fused
    float vA = b4[0], vB = vA;
#pragma unroll
    for (int o = 0; o < 36; ++o) {
        v2f aA = { b3[o], 0.0f };
        v2f aB = aA;
#pragma unroll
        for (int q = 0; q < 18; ++q) {
            const v2f wq = w3v[o * 18 + q];
            aA = fma2(wq, h2a[q], aA);
            aB = fma2(wq, h2b[q], aB);
        }
        const float w4o = w4[o];
        vA = fmaf(w4o, fmaxf(aA.x + aA.y, 0.0f), vA);
        vB = fmaf(w4o, fmaxf(aB.x + aB.y, 0.0f), vB);
    }

    if (posA < maxk) {   // never overflows statistically at maxk>=64
        uint2 e;
        e.x = __float_as_uint(vA);
        e.y = ((unsigned)i << 8) | (unsigned)hw2.x;
        list[(size_t)hw2.y * maxk + posA] = e;
    }
    if (posB < maxk) {
        uint2 e;
        e.x = __float_as_uint(vB);
        e.y = ((unsigned)(i + 1) << 8) | (unsigned)hw2.z;
        list[(size_t)hw2.w * maxk + posB] = e;
    }
}

// Wave-local LDS ordering: drain this wave's outstanding DS ops. "memory"
// clobber orders surrounding memory ops (consumers here are ds ops, so the
// clobber suffices; rule-#18 hazard applies only to reg-only consumers).
__device__ __forceinline__ void lds_wave_fence() {
    asm volatile("s_waitcnt lgkmcnt(0)" ::: "memory");
}

// ---------------------------------------------------------------------------
// Kernel B v3 (unchanged from R4): 32-bit dedup keys, native ds_max_u32,
// grid-stride 2200 blocks x 4 waves x 8 cols, barrier-free.
// Key = (i<<8)|row (28 bits) = e.y; winner per row = max key; lane
// re-identifies via tbl[row]==e.y and contributes its own e.x.
// ---------------------------------------------------------------------------
__global__ void __launch_bounds__(256) colmax_kernel(
    const int* __restrict__ tindex,
    const int* __restrict__ counts,
    const uint2* __restrict__ list,
    float* __restrict__ out,
    int maxk)
{
    __shared__ unsigned rowwin[4][200];
    const int lane = threadIdx.x;        // 0..63
    const int y    = threadIdx.y;        // 0..3
    unsigned* tbl = rowwin[y];

    const bool empty = (tindex[0] == -1);

    if (blockIdx.x == 0 && lane == 0 && y == 0)
        out[W_DIM] = empty ? 0.0f : 1.0f;    // flag output

    // zero the full per-wave table once (rows 0..199)
    tbl[lane]       = 0u;
    tbl[lane + 64]  = 0u;
    tbl[lane + 128] = 0u;
    if (lane < 8) tbl[lane + 192] = 0u;
    lds_wave_fence();

    const int step = gridDim.x * 4;
    for (int w = blockIdx.x * 4 + y; w < W_DIM; w += step) {
        int c = 0;
        if (!empty) {
            c = counts[w];
            if (c > maxk) c = maxk;
        }

        uint2 e = make_uint2(0u, 0u);
        const bool have = (lane < c);
        float v = FILL_V;
        if (have) {
            e = list[(size_t)w * maxk + lane];
            atomicMax(&tbl[e.y & 0xFFu], e.y);   // native ds_max_u32
        }
        lds_wave_fence();                 // all lanes' maxes visible
        if (have) {
            if (tbl[e.y & 0xFFu] == e.y)  // unique keys -> exactly one winner/row
                v = __uint_as_float(e.x);
            tbl[e.y & 0xFFu] = 0u;        // re-zero only dirtied rows
        }
        lds_wave_fence();                 // zeros land before next column

#pragma unroll
        for (int off = 32; off > 0; off >>= 1)
            v = fmaxf(v, __shfl_down(v, off, 64));

        if (lane == 0) out[w] = v;
    }
}

extern "C" void kernel_launch(void* const* d_in, const int* in_sizes, int n_in,
                              void* d_out, int out_size, void* d_ws, size_t ws_size,
                              hipStream_t stream) {
    const float* input  = (const float*)d_in[0];
    const int*   tindex = (const int*)d_in[1];   // int32 on device
    const float* w1 = (const float*)d_in[2];
    const float* b1 = (const float*)d_in[3];
    const float* w2 = (const float*)d_in[4];
    const float* b2 = (const float*)d_in[5];
    const float* w3 = (const float*)d_in[6];
    const float* b3 = (const float*)d_in[7];
    const float* w4 = (const float*)d_in[8];
    const float* b4 = (const float*)d_in[9];
    float* out = (float*)d_out;

    // workspace: counts [70400 int] | list [70400][maxk] uint2
    int*   counts = (int*)d_ws;
    uint2* list   = (uint2*)((char*)d_ws + (size_t)W_DIM * sizeof(int));

    size_t avail = (ws_size > (size_t)W_DIM * sizeof(int))
                       ? ws_size - (size_t)W_DIM * sizeof(int) : 0;
    int maxk = (int)(avail / ((size_t)W_DIM * sizeof(uint2)));
    if (maxk > 64) maxk = 64;
    if (maxk < 1)  maxk = 1;

    (void)hipMemsetAsync(counts, 0, (size_t)W_DIM * sizeof(int), stream);

    // 2 points per thread: 500000 threads -> 1954 blocks
    mlp_scatter_kernel<<<(N_PTS / 2 + 255) / 256, 256, 0, stream>>>(
        input, tindex, w1, b1, w2, b2, w3, b3, w4, b4, counts, list, maxk);

    // grid-stride: 2200 blocks x 4 waves x 8 columns = 70400 exactly
    colmax_kernel<<<2200, dim3(64, 4), 0, stream>>>(
        tindex, counts, list, out, maxk);
}